// Round 9
// baseline (331.168 us; speedup 1.0000x reference)
//
#include <hip/hip_runtime.h>

#define N_NODES 50000
#define N_EDGES 800000
#define FEAT 64
#define HID 128
#define N_TYPES 4
#define N_REL 3
#define N_LAYERS 2
#define LN_EPS 1e-5f
#define NROWS 50016   // 50000 padded to 32 (1563 groups of 32)
#define NG32 1563
#define CAP 64        // per-dst bucket capacity
#define NBKT 196      // coarse buckets: dst>>8
#define CAP1 4608     // coarse bucket capacity (mean 4082, +8 sigma)
#define EPB 4096      // edges per bin1 block
#define BINCAP 56     // per-block per-bin LDS capacity (mean 20.9, +7.7 sigma)
#define NCOMBO 400    // 100 z-values x 4 types
#define WT_STRIDE 136

typedef __attribute__((ext_vector_type(8))) short bf16x8;
typedef __attribute__((ext_vector_type(16))) float f32x16;
typedef __attribute__((ext_vector_type(2))) float f32x2;

static __device__ inline unsigned short f2bf(float f) {
    unsigned int u = __float_as_uint(f);
    return (unsigned short)((u + 0x7fffu + ((u >> 16) & 1u)) >> 16);
}
static __device__ inline unsigned int packbf2(float lo, float hi) {
    return (unsigned int)f2bf(lo) | ((unsigned int)f2bf(hi) << 16);
}

// decode 8 fp8-e4m3 (uint2) -> accumulate into a[0..7]
static __device__ inline void acc8_fp8(float* a, uint2 w) {
    f32x2 d0 = __builtin_amdgcn_cvt_pk_f32_fp8((int)w.x, false);
    f32x2 d1 = __builtin_amdgcn_cvt_pk_f32_fp8((int)w.x, true);
    f32x2 d2 = __builtin_amdgcn_cvt_pk_f32_fp8((int)w.y, false);
    f32x2 d3 = __builtin_amdgcn_cvt_pk_f32_fp8((int)w.y, true);
    a[0] += d0[0]; a[1] += d0[1]; a[2] += d1[0]; a[3] += d1[1];
    a[4] += d2[0]; a[5] += d2[1]; a[6] += d3[0]; a[7] += d3[1];
}
// decode 8 fp8-e4m3 (uint2) -> bf16x8 (lossless: e4m3 values are exact in bf16)
static __device__ inline bf16x8 f8_to_bf16x8(uint2 w) {
    f32x2 d0 = __builtin_amdgcn_cvt_pk_f32_fp8((int)w.x, false);
    f32x2 d1 = __builtin_amdgcn_cvt_pk_f32_fp8((int)w.x, true);
    f32x2 d2 = __builtin_amdgcn_cvt_pk_f32_fp8((int)w.y, false);
    f32x2 d3 = __builtin_amdgcn_cvt_pk_f32_fp8((int)w.y, true);
    union { bf16x8 v; unsigned int u[4]; } r;
    r.u[0] = packbf2(d0[0], d0[1]);
    r.u[1] = packbf2(d1[0], d1[1]);
    r.u[2] = packbf2(d2[0], d2[1]);
    r.u[3] = packbf2(d3[0], d3[1]);
    return r.v;
}

// ---------------------------------------------------------------------------
// MERGED front-end: blocks [0,196) = edge binning (+combo), [196,596) =
// encoder/layer-1 tables, [596,852) = layer-2 weight prep + pooled zero.
__global__ __launch_bounds__(256) void build_tables_kernel(
    const int* __restrict__ src, const int* __restrict__ dst,
    const int* __restrict__ et, const int* __restrict__ z,
    const int* __restrict__ nt,
    const float* __restrict__ z_embed, const float* __restrict__ w1,
    const float* __restrict__ b1, const float* __restrict__ w2,
    const float* __restrict__ b2, const float* __restrict__ rel_w,
    const float* __restrict__ lin_w, const float* __restrict__ lin_b,
    unsigned short* __restrict__ combo, int* __restrict__ bcnt,
    int* __restrict__ bucket, unsigned int* __restrict__ ytab,
    float* __restrict__ lintab, unsigned short* __restrict__ wbuf,
    float* __restrict__ pooled) {
    __shared__ int lbin[NBKT * BINCAP];  // 43.9 KB (bin1 branch only)
    __shared__ int lcnt[NBKT];
    __shared__ int lbase[NBKT];
    __shared__ float h[HID];             // encoder branch only
    __shared__ float xrow[HID];
    __shared__ float tmp[HID];

    int b = blockIdx.x;
    if (b < NBKT) {
        // ---- bin1: bin edges by dst>>8. Packed: src|et<<16|(dst&255)<<18 ----
        int ci = b * 256 + threadIdx.x;
        if (ci < N_NODES) combo[ci] = (unsigned short)(z[ci] * 4 + nt[ci]);
        for (int i = threadIdx.x; i < NBKT; i += 256) lcnt[i] = 0;
        __syncthreads();
        int base = b * EPB;
#pragma unroll
        for (int i = 0; i < EPB / 256; ++i) {
            int e = base + i * 256 + threadIdx.x;
            if (e < N_EDGES) {
                int d = dst[e];
                int bk = d >> 8;
                int v = src[e] | (et[e] << 16) | ((d & 255) << 18);
                int pos = atomicAdd(&lcnt[bk], 1);
                if (pos < BINCAP) lbin[bk * BINCAP + pos] = v;
            }
        }
        __syncthreads();
        if (threadIdx.x < NBKT) {
            int c = min(lcnt[threadIdx.x], BINCAP);
            lcnt[threadIdx.x] = c;
            lbase[threadIdx.x] = atomicAdd(&bcnt[threadIdx.x], c);
        }
        __syncthreads();
        int wv = threadIdx.x >> 6, ln = threadIdx.x & 63;
        for (int bb = wv; bb < NBKT; bb += 4) {
            int c = lcnt[bb];
            if (ln < c) {
                int gp = lbase[bb] + ln;
                if (gp < CAP1) bucket[bb * CAP1 + gp] = lbin[bb * BINCAP + ln];
            }
        }
        return;
    }
    if (b >= NBKT + NCOMBO) {
        // ---- weight prep for layer 2: 256 blocks x 256 threads = 65536 ----
        int pb = b - (NBKT + NCOMBO);
        if (pb == 0 && threadIdx.x < HID) pooled[threadIdx.x] = 0.0f;
        int idx = pb * 256 + threadIdx.x;
        int k = idx & 127;
        int col = (idx >> 7) & 127;
        int mat = idx >> 14;
        float w = (mat < 3) ? rel_w[(((size_t)(3 + mat)) * HID + k) * HID + col]
                            : lin_w[((size_t)(HID + k)) * HID + col];
        wbuf[(size_t)mat * HID * WT_STRIDE + col * WT_STRIDE + k] = f2bf(w);
        return;
    }
    // ---- encoder + layer-1 tables (one combo per block; threads<128 act) ----
    int c = b - NBKT;  // 0..399
    int zi = c >> 2;
    int t = c & 3;
    int j = threadIdx.x;
    bool act = j < HID;
    if (act) {
        float acc = b1[t * HID + j];
#pragma unroll 8
        for (int k = 0; k < FEAT; ++k)
            acc = fmaf(z_embed[zi * FEAT + k], w1[((size_t)t * FEAT + k) * HID + j], acc);
        h[j] = fmaxf(acc, 0.0f);
    }
    __syncthreads();
    if (act) {
        float acc2 = b2[t * HID + j];
#pragma unroll 8
        for (int k = 0; k < HID; ++k)
            acc2 = fmaf(h[k], w2[(size_t)t * HID * HID + k * HID + j], acc2);
        xrow[j] = acc2;
    }
    __syncthreads();
#pragma unroll 1
    for (int r = 0; r < N_REL; ++r) {
        if (act) {
            float a = 0.f;
            const float* W = rel_w + (size_t)r * HID * HID;  // layer 0
#pragma unroll 8
            for (int k = 0; k < HID; ++k) a = fmaf(xrow[k], W[k * HID + j], a);
            tmp[j] = a;
        }
        __syncthreads();
        if (j < 32) {  // pack 4 fp8 per uint
            int w0 = __builtin_amdgcn_cvt_pk_fp8_f32(tmp[4 * j], tmp[4 * j + 1], 0, false);
            w0 = __builtin_amdgcn_cvt_pk_fp8_f32(tmp[4 * j + 2], tmp[4 * j + 3], w0, true);
            ytab[(r * NCOMBO + c) * 32 + j] = (unsigned)w0;
        }
        __syncthreads();
    }
    if (act) {
        float a = lin_b[j];
#pragma unroll 8
        for (int k = 0; k < HID; ++k) a = fmaf(xrow[k], lin_w[k * HID + j], a);
        lintab[c * HID + j] = a;
    }
}

// ---------------------------------------------------------------------------
// Pass 2: RELATION-SORTED scatter into padded per-node buckets.
// Final payload word: src(16) | combo(src)(9)<<18. cnt3 = c0|c1<<8|c2<<16.
__global__ __launch_bounds__(256) void build2_kernel(const int* __restrict__ bcnt,
                                                     const int* __restrict__ bucket,
                                                     const unsigned short* __restrict__ combo,
                                                     int* __restrict__ cnt3,
                                                     int* __restrict__ payload) {
    __shared__ int lcnt[256 * 3];
    for (int i = threadIdx.x; i < 768; i += 256) lcnt[i] = 0;
    __syncthreads();
    int b = blockIdx.x;
    int n0 = b << 8;
    int cb = min(bcnt[b], CAP1);
    const int* bk = bucket + b * CAP1;
    for (int i = threadIdx.x; i < cb; i += 256) {
        int v = bk[i];
        atomicAdd(&lcnt[((v >> 18) & 255) * 3 + ((v >> 16) & 3)], 1);
    }
    __syncthreads();
    int t = threadIdx.x;
    int c0 = min(lcnt[t * 3 + 0], CAP);
    int c1 = min(lcnt[t * 3 + 1], CAP - c0);
    int c2 = min(lcnt[t * 3 + 2], CAP - c0 - c1);
    __syncthreads();
    lcnt[t * 3 + 0] = 0;
    lcnt[t * 3 + 1] = c0;
    lcnt[t * 3 + 2] = c0 + c1;
    int node = n0 + t;
    if (node < N_NODES) cnt3[node] = c0 | (c1 << 8) | (c2 << 16);
    __syncthreads();
    for (int i = threadIdx.x; i < cb; i += 256) {
        int v = bk[i];
        int dl = (v >> 18) & 255;
        int r = (v >> 16) & 3;
        int sc = v & 0xffff;
        int pos = atomicAdd(&lcnt[dl * 3 + r], 1);
        if (pos < CAP)
            payload[((n0 + dl) << 6) + pos] = sc | ((int)combo[sc] << 18);
    }
}

// ---------------------------------------------------------------------------
// LAYER 1 fused: branch-free fp8 segment gather from ytab + lintab + LN.
// Emits xf8 in DE-INTERLEAVED slot order: channel-block c -> slot
// (c>>1)+((c&1)<<3), so a fused_layer lane's 8 fragments are 64B contiguous.
__global__ __launch_bounds__(256) void gather_ln1_kernel(
    const int* __restrict__ cnt3, const int* __restrict__ payload,
    const uint2* __restrict__ ytab8, const float* __restrict__ lintab,
    const unsigned short* __restrict__ combo, const float* __restrict__ lng,
    const float* __restrict__ lnb, uint2* __restrict__ xf8) {
    int tid = blockIdx.x * 256 + threadIdx.x;
    int node = tid >> 4;  // 3125 blocks exact
    int l16 = tid & 15;
    int c3 = cnt3[node];
    int c0 = c3 & 255, c1 = (c3 >> 8) & 255, c2 = (c3 >> 16) & 255;
    int tot = c0 + c1 + c2;
    float inv = 1.0f / (float)max(tot, 1);
    const int* pl = payload + (node << 6);
    float a[8] = {};
    int e = 0;
#pragma unroll 1
    for (int r = 0; r < 3; ++r) {
        int e1 = (r == 0) ? c0 : (r == 1) ? c0 + c1 : tot;
        int base = (r * NCOMBO) << 4;
        for (; e + 4 <= e1; e += 4) {
            int pA = pl[e], pB = pl[e + 1], pC = pl[e + 2], pD = pl[e + 3];
            uint2 vA = ytab8[base + ((pA >> 18) << 4) + l16];
            uint2 vB = ytab8[base + ((pB >> 18) << 4) + l16];
            uint2 vC = ytab8[base + ((pC >> 18) << 4) + l16];
            uint2 vD = ytab8[base + ((pD >> 18) << 4) + l16];
            acc8_fp8(a, vA);
            acc8_fp8(a, vB);
            acc8_fp8(a, vC);
            acc8_fp8(a, vD);
        }
        if (e + 2 <= e1) {
            int pA = pl[e], pB = pl[e + 1];
            uint2 vA = ytab8[base + ((pA >> 18) << 4) + l16];
            uint2 vB = ytab8[base + ((pB >> 18) << 4) + l16];
            acc8_fp8(a, vA);
            acc8_fp8(a, vB);
            e += 2;
        }
        if (e < e1) {
            int p = pl[e]; ++e;
            acc8_fp8(a, ytab8[base + ((p >> 18) << 4) + l16]);
        }
    }
    const float* lrow = lintab + (int)combo[node] * HID + l16 * 8;
    float v[8], s = 0.f, q = 0.f;
#pragma unroll
    for (int j = 0; j < 8; ++j) {
        v[j] = fmaf(a[j], inv, lrow[j]);
        s += v[j];
        q += v[j] * v[j];
    }
#pragma unroll
    for (int mk = 1; mk < 16; mk <<= 1) {
        s += __shfl_xor(s, mk);
        q += __shfl_xor(q, mk);
    }
    float mu = s * (1.0f / HID);
    float rstd = rsqrtf(q * (1.0f / HID) - mu * mu + LN_EPS);
    const float* g8 = lng + l16 * 8;
    const float* b8 = lnb + l16 * 8;
    float o[8];
#pragma unroll
    for (int j = 0; j < 8; ++j) o[j] = (v[j] - mu) * rstd * g8[j] + b8[j];
    int lo = 0, hi = 0;
    lo = __builtin_amdgcn_cvt_pk_fp8_f32(o[0], o[1], lo, false);
    lo = __builtin_amdgcn_cvt_pk_fp8_f32(o[2], o[3], lo, true);
    hi = __builtin_amdgcn_cvt_pk_fp8_f32(o[4], o[5], hi, false);
    hi = __builtin_amdgcn_cvt_pk_fp8_f32(o[6], o[7], hi, true);
    int slot = (l16 >> 1) + ((l16 & 1) << 3);   // de-interleave
    xf8[(node << 4) + slot] = make_uint2((unsigned)lo, (unsigned)hi);
}

// ---------------------------------------------------------------------------
// LAYER 2 gather over fp8 rows (8B/lane): branch-free segments, fp32 accum,
// fp8 s_r stores in the same de-interleaved slot order as xf8.
__global__ __launch_bounds__(256) void gather3_kernel(const int* __restrict__ cnt3,
                                                      const int* __restrict__ payload,
                                                      const uint2* __restrict__ xf8,
                                                      uint2* __restrict__ s0,
                                                      uint2* __restrict__ s1,
                                                      uint2* __restrict__ s2) {
    int tid = blockIdx.x * 256 + threadIdx.x;
    int node = tid >> 4;
    int l16 = tid & 15;
    int slot = (l16 >> 1) + ((l16 & 1) << 3);   // de-interleaved slot of block l16
    int c3 = cnt3[node];
    int c0 = c3 & 255, c1 = (c3 >> 8) & 255, c2 = (c3 >> 16) & 255;
    int tot = c0 + c1 + c2;
    float inv = 1.0f / (float)max(tot, 1);
    const int* pl = payload + (node << 6);
    int o = node * 16 + slot;
    int e = 0;
#pragma unroll 1
    for (int r = 0; r < 3; ++r) {
        int e1 = (r == 0) ? c0 : (r == 1) ? c0 + c1 : tot;
        float a[8] = {};
        for (; e + 4 <= e1; e += 4) {
            int pA = pl[e], pB = pl[e + 1], pC = pl[e + 2], pD = pl[e + 3];
            uint2 vA = xf8[((pA & 0xffff) << 4) + slot];
            uint2 vB = xf8[((pB & 0xffff) << 4) + slot];
            uint2 vC = xf8[((pC & 0xffff) << 4) + slot];
            uint2 vD = xf8[((pD & 0xffff) << 4) + slot];
            acc8_fp8(a, vA);
            acc8_fp8(a, vB);
            acc8_fp8(a, vC);
            acc8_fp8(a, vD);
        }
        if (e + 2 <= e1) {
            int pA = pl[e], pB = pl[e + 1];
            uint2 vA = xf8[((pA & 0xffff) << 4) + slot];
            uint2 vB = xf8[((pB & 0xffff) << 4) + slot];
            acc8_fp8(a, vA);
            acc8_fp8(a, vB);
            e += 2;
        }
        if (e < e1) {
            int p = pl[e]; ++e;
            acc8_fp8(a, xf8[((p & 0xffff) << 4) + slot]);
        }
        int lo = 0, hi = 0;
        lo = __builtin_amdgcn_cvt_pk_fp8_f32(a[0] * inv, a[1] * inv, lo, false);
        lo = __builtin_amdgcn_cvt_pk_fp8_f32(a[2] * inv, a[3] * inv, lo, true);
        hi = __builtin_amdgcn_cvt_pk_fp8_f32(a[4] * inv, a[5] * inv, hi, false);
        hi = __builtin_amdgcn_cvt_pk_fp8_f32(a[6] * inv, a[7] * inv, hi, true);
        uint2 w = make_uint2((unsigned)lo, (unsigned)hi);
        if (r == 0) s0[o] = w;
        else if (r == 1) s1[o] = w;
        else s2[o] = w;
    }
}

// ---------------------------------------------------------------------------
// Layer-2 fused GEMM+LN+pool. R9: NO weight LDS — B-fragments read straight
// from wbuf (139 KB, read-only, L2-resident per XCD). Removes the 1-block/CU
// LDS cap (the diagnosed bottleneck: ~4 A-requests in flight per wave, 8
// waves/CU): grid 784 -> 3-4 blocks/CU = 24-32 waves/CU, 3-4x MLP.
// A-streams fp8, de-interleaved: 4 x uint4 per mat (was 8 x uint2).
__global__ __launch_bounds__(512) void fused_layer_kernel(
    const uint4* __restrict__ s0, const uint4* __restrict__ s1,
    const uint4* __restrict__ s2, const uint4* __restrict__ xf8,
    const unsigned short* __restrict__ wbuf, const float* __restrict__ lb,
    const float* __restrict__ lng, const float* __restrict__ lnb,
    float* __restrict__ pooled, const float* __restrict__ reg_w,
    const float* __restrict__ reg_b, float* __restrict__ out,
    int* __restrict__ done) {
    __shared__ float csh[3 * HID];
    __shared__ float pooled_sh[HID];
    __shared__ int lastFlag;

    int wave = threadIdx.x >> 6;
    int lane = threadIdx.x & 63;
    int n32 = lane & 31;
    int hf = lane >> 5;

    int g0 = wave * gridDim.x + blockIdx.x;
    bool active = g0 < NG32;
    int abase = active ? ((g0 * 32 + n32) * 8 + hf * 4) : 0;  // uint4 index

    uint4 bufA[4], bufB[4];
    // issue-early: mats 0,1 (8 x 16B loads) before the csh barrier
    {
        const uint4* p0 = s0 + abase;
        const uint4* p1 = s1 + abase;
#pragma unroll
        for (int i = 0; i < 4; ++i) { bufA[i] = p0[i]; bufB[i] = p1[i]; }
    }

    if (threadIdx.x < HID) {
        pooled_sh[threadIdx.x] = 0.0f;
        csh[threadIdx.x] = lb[threadIdx.x];
        csh[HID + threadIdx.x] = lng[threadIdx.x];
        csh[2 * HID + threadIdx.x] = lnb[threadIdx.x];
    }
    __syncthreads();

    float pacc[4] = {0.f, 0.f, 0.f, 0.f};

    if (active) {
        f32x16 acc[4];
#pragma unroll
        for (int ct = 0; ct < 4; ++ct)
#pragma unroll
            for (int i = 0; i < 16; ++i) acc[ct][i] = 0.0f;

        const unsigned short* wlane = wbuf + n32 * WT_STRIDE + hf * 8;

        // consume 8 fp8 fragments of `buf` against weight mat m (B from global)
#define DOMAT(buf, m)                                                          \
        {                                                                      \
            const unsigned short* wm = wlane + (size_t)(m) * (HID * WT_STRIDE);\
            _Pragma("unroll")                                                  \
            for (int t = 0; t < 8; ++t) {                                      \
                uint2 f = (t & 1) ? make_uint2(buf[t >> 1].z, buf[t >> 1].w)   \
                                  : make_uint2(buf[t >> 1].x, buf[t >> 1].y);  \
                bf16x8 afr = f8_to_bf16x8(f);                                  \
                _Pragma("unroll")                                              \
                for (int ct = 0; ct < 4; ++ct) {                               \
                    bf16x8 bfr = *(const bf16x8*)(wm + ct * 32 * WT_STRIDE + t * 16); \
                    acc[ct] = __builtin_amdgcn_mfma_f32_32x32x16_bf16(         \
                        afr, bfr, acc[ct], 0, 0, 0);                           \
                }                                                              \
            }                                                                  \
        }
#define LDMAT(buf, srcp)                                                       \
        {                                                                      \
            const uint4* _p = (srcp) + abase;                                  \
            _Pragma("unroll")                                                  \
            for (int i = 0; i < 4; ++i) buf[i] = _p[i];                        \
        }

        DOMAT(bufA, 0);    // loads long since issued
        LDMAT(bufA, s2);   // issue mat2
        DOMAT(bufB, 1);
        LDMAT(bufB, xf8);  // issue mat3 (lin path, fp8 x)
        DOMAT(bufA, 2);
        DOMAT(bufB, 3);
#undef DOMAT
#undef LDMAT

        int node0 = g0 * 32;
#pragma unroll
        for (int reg = 0; reg < 16; ++reg) {
            int row = node0 + (reg & 3) + 8 * (reg >> 2) + 4 * hf;
            float v[4];
            float s = 0.f, q = 0.f;
#pragma unroll
            for (int ct = 0; ct < 4; ++ct) {
                v[ct] = acc[ct][reg] + csh[ct * 32 + n32];
                s += v[ct];
                q += v[ct] * v[ct];
            }
#pragma unroll
            for (int mk = 1; mk < 32; mk <<= 1) {
                s += __shfl_xor(s, mk);
                q += __shfl_xor(q, mk);
            }
            float mu = s * (1.0f / HID);
            float rstd = rsqrtf(q * (1.0f / HID) - mu * mu + LN_EPS);
            if (row < N_NODES) {
#pragma unroll
                for (int ct = 0; ct < 4; ++ct) {
                    int col = ct * 32 + n32;
                    pacc[ct] += (v[ct] - mu) * rstd * csh[HID + col] + csh[2 * HID + col];
                }
            }
        }
    }

#pragma unroll
    for (int ct = 0; ct < 4; ++ct) {
        float t = pacc[ct] + __shfl_xor(pacc[ct], 32);
        if (hf == 0 && t != 0.0f) atomicAdd(&pooled_sh[ct * 32 + n32], t);
    }
    __syncthreads();
    if (threadIdx.x < HID) atomicAdd(&pooled[threadIdx.x], pooled_sh[threadIdx.x]);

    // ---- folded final reduction (last block) ----
    __threadfence();
    __syncthreads();
    if (threadIdx.x == 0)
        lastFlag = (atomicAdd(done, 1) == (int)gridDim.x - 1);
    __syncthreads();
    if (lastFlag && threadIdx.x < 64) {
        int l = threadIdx.x;
        // atomic fetch-add(0) reads take the same coherent path as the writes
        float s = atomicAdd(&pooled[l], 0.0f) * reg_w[l] +
                  atomicAdd(&pooled[64 + l], 0.0f) * reg_w[64 + l];
#pragma unroll
        for (int o = 32; o; o >>= 1) s += __shfl_down(s, o);
        if (l == 0) out[0] = s * (1.0f / N_NODES) + reg_b[0];
    }
}

// ---------------------------------------------------------------------------
extern "C" void kernel_launch(void* const* d_in, const int* in_sizes, int n_in,
                              void* d_out, int out_size, void* d_ws, size_t ws_size,
                              hipStream_t stream) {
    const int* z = (const int*)d_in[0];
    const int* nt = (const int*)d_in[1];
    const int* ei = (const int*)d_in[2];
    const int* et = (const int*)d_in[3];
    const float* z_embed = (const float*)d_in[4];
    const float* enc_w1 = (const float*)d_in[5];
    const float* enc_b1 = (const float*)d_in[6];
    const float* enc_w2 = (const float*)d_in[7];
    const float* enc_b2 = (const float*)d_in[8];
    const float* lin_w = (const float*)d_in[9];
    const float* lin_b = (const float*)d_in[10];
    const float* rel_w = (const float*)d_in[11];
    const float* ln_g = (const float*)d_in[12];
    const float* ln_b = (const float*)d_in[13];
    const float* reg_w = (const float*)d_in[14];
    const float* reg_b = (const float*)d_in[15];
    float* out = (float*)d_out;

    const size_t NHf8 = (size_t)NROWS * HID;  // bytes per fp8 feature plane
    char* p = (char*)d_ws;
    uint2* xf8 = (uint2*)p;                     p += NHf8;   // 6.4 MB
    uint2* s0 = (uint2*)p;                      p += NHf8;   // fp8 means
    uint2* s1 = (uint2*)p;                      p += NHf8;
    uint2* s2 = (uint2*)p;                      p += NHf8;
    unsigned short* wbuf = (unsigned short*)p;  p += (size_t)4 * HID * WT_STRIDE * 2;
    unsigned int* ytab = (unsigned int*)p;      p += (size_t)N_REL * NCOMBO * HID;  // fp8
    float* lintab = (float*)p;                  p += NCOMBO * HID * 4;
    unsigned short* combo = (unsigned short*)p; p += N_NODES * 2;
    float* pooled = (float*)p;                  p += HID * 4;
    int* cnt3 = (int*)p;                        p += N_NODES * 4;
    int* bcnt = (int*)p;                        p += NBKT * 4;
    int* done = (int*)p;                        p += 4;        // adjacent to bcnt
    int* bucket = (int*)p;                      p += (size_t)NBKT * CAP1 * 4;
    int* payload = (int*)p;                     p += (size_t)N_NODES * CAP * 4;

    const int* src = ei;
    const int* dst = ei + N_EDGES;

    hipMemsetAsync(bcnt, 0, (NBKT + 1) * sizeof(int), stream);  // bcnt + done

    // front-end: edge binning || encoder tables || weight prep (one dispatch)
    build_tables_kernel<<<NBKT + NCOMBO + 256, 256, 0, stream>>>(
        src, dst, et, z, nt, z_embed, enc_w1, enc_b1, enc_w2, enc_b2,
        rel_w, lin_w, lin_b, combo, bcnt, bucket, ytab, lintab, wbuf, pooled);

    build2_kernel<<<NBKT, 256, 0, stream>>>(bcnt, bucket, combo, cnt3, payload);

    // layer 1: fused fp8 table-gather + lin + LN -> xf8 (fp8, de-interleaved)
    gather_ln1_kernel<<<3125, 256, 0, stream>>>(cnt3, payload, (const uint2*)ytab, lintab,
                                                combo, ln_g, ln_b, xf8);
    // layer 2: fp8 gather -> fp8 means; LDS-free MFMA fused layer
    gather3_kernel<<<3125, 256, 0, stream>>>(cnt3, payload, xf8, s0, s1, s2);
    fused_layer_kernel<<<784, 512, 0, stream>>>(
        (const uint4*)s0, (const uint4*)s1, (const uint4*)s2, (const uint4*)xf8,
        wbuf, lin_b + HID, ln_g + HID, ln_b + HID,
        pooled, reg_w, reg_b, out, done);
}

// Round 11
// 232.923 us; speedup vs baseline: 1.4218x; 1.4218x over previous
//
#include <hip/hip_runtime.h>

#define N_NODES 50000
#define N_EDGES 800000
#define FEAT 64
#define HID 128
#define N_TYPES 4
#define N_REL 3
#define N_LAYERS 2
#define LN_EPS 1e-5f
#define NROWS 50016   // 50000 padded to 32
#define NG16 3125     // 16-node groups: 3125 x 16 = 50000 exactly
#define CAP 64        // per-dst bucket capacity
#define NBKT 196      // coarse buckets: dst>>8
#define CAP1 4608     // coarse bucket capacity (mean 4082, +8 sigma)
#define EPB 4096      // edges per bin1 block
#define BINCAP 56     // per-block per-bin LDS capacity (mean 20.9, +7.7 sigma)
#define NCOMBO 400    // 100 z-values x 4 types
#define WT_STRIDE 136

typedef __attribute__((ext_vector_type(8))) short bf16x8;
typedef __attribute__((ext_vector_type(4))) float f32x4;
typedef __attribute__((ext_vector_type(2))) float f32x2;

static __device__ inline unsigned short f2bf(float f) {
    unsigned int u = __float_as_uint(f);
    return (unsigned short)((u + 0x7fffu + ((u >> 16) & 1u)) >> 16);
}
static __device__ inline unsigned int packbf2(float lo, float hi) {
    return (unsigned int)f2bf(lo) | ((unsigned int)f2bf(hi) << 16);
}

// decode 8 fp8-e4m3 (uint2) -> accumulate into a[0..7]
static __device__ inline void acc8_fp8(float* a, uint2 w) {
    f32x2 d0 = __builtin_amdgcn_cvt_pk_f32_fp8((int)w.x, false);
    f32x2 d1 = __builtin_amdgcn_cvt_pk_f32_fp8((int)w.x, true);
    f32x2 d2 = __builtin_amdgcn_cvt_pk_f32_fp8((int)w.y, false);
    f32x2 d3 = __builtin_amdgcn_cvt_pk_f32_fp8((int)w.y, true);
    a[0] += d0[0]; a[1] += d0[1]; a[2] += d1[0]; a[3] += d1[1];
    a[4] += d2[0]; a[5] += d2[1]; a[6] += d3[0]; a[7] += d3[1];
}
// decode 8 fp8-e4m3 (uint2) -> bf16x8 (lossless: e4m3 values are exact in bf16)
static __device__ inline bf16x8 f8_to_bf16x8(uint2 w) {
    f32x2 d0 = __builtin_amdgcn_cvt_pk_f32_fp8((int)w.x, false);
    f32x2 d1 = __builtin_amdgcn_cvt_pk_f32_fp8((int)w.x, true);
    f32x2 d2 = __builtin_amdgcn_cvt_pk_f32_fp8((int)w.y, false);
    f32x2 d3 = __builtin_amdgcn_cvt_pk_f32_fp8((int)w.y, true);
    union { bf16x8 v; unsigned int u[4]; } r;
    r.u[0] = packbf2(d0[0], d0[1]);
    r.u[1] = packbf2(d1[0], d1[1]);
    r.u[2] = packbf2(d2[0], d2[1]);
    r.u[3] = packbf2(d3[0], d3[1]);
    return r.v;
}

// ---------------------------------------------------------------------------
// MERGED front-end: blocks [0,196) = edge binning (+combo), [196,596) =
// encoder/layer-1 tables, [596,852) = layer-2 weight prep + pooled zero.
__global__ __launch_bounds__(256) void build_tables_kernel(
    const int* __restrict__ src, const int* __restrict__ dst,
    const int* __restrict__ et, const int* __restrict__ z,
    const int* __restrict__ nt,
    const float* __restrict__ z_embed, const float* __restrict__ w1,
    const float* __restrict__ b1, const float* __restrict__ w2,
    const float* __restrict__ b2, const float* __restrict__ rel_w,
    const float* __restrict__ lin_w, const float* __restrict__ lin_b,
    unsigned short* __restrict__ combo, int* __restrict__ bcnt,
    int* __restrict__ bucket, unsigned int* __restrict__ ytab,
    float* __restrict__ lintab, unsigned short* __restrict__ wbuf,
    float* __restrict__ pooled) {
    __shared__ int lbin[NBKT * BINCAP];  // 43.9 KB (bin1 branch only)
    __shared__ int lcnt[NBKT];
    __shared__ int lbase[NBKT];
    __shared__ float h[HID];             // encoder branch only
    __shared__ float xrow[HID];
    __shared__ float tmp[HID];

    int b = blockIdx.x;
    if (b < NBKT) {
        // ---- bin1: bin edges by dst>>8. Packed: src|et<<16|(dst&255)<<18 ----
        int ci = b * 256 + threadIdx.x;
        if (ci < N_NODES) combo[ci] = (unsigned short)(z[ci] * 4 + nt[ci]);
        for (int i = threadIdx.x; i < NBKT; i += 256) lcnt[i] = 0;
        __syncthreads();
        int base = b * EPB;
#pragma unroll
        for (int i = 0; i < EPB / 256; ++i) {
            int e = base + i * 256 + threadIdx.x;
            if (e < N_EDGES) {
                int d = dst[e];
                int bk = d >> 8;
                int v = src[e] | (et[e] << 16) | ((d & 255) << 18);
                int pos = atomicAdd(&lcnt[bk], 1);
                if (pos < BINCAP) lbin[bk * BINCAP + pos] = v;
            }
        }
        __syncthreads();
        if (threadIdx.x < NBKT) {
            int c = min(lcnt[threadIdx.x], BINCAP);
            lcnt[threadIdx.x] = c;
            lbase[threadIdx.x] = atomicAdd(&bcnt[threadIdx.x], c);
        }
        __syncthreads();
        int wv = threadIdx.x >> 6, ln = threadIdx.x & 63;
        for (int bb = wv; bb < NBKT; bb += 4) {
            int c = lcnt[bb];
            if (ln < c) {
                int gp = lbase[bb] + ln;
                if (gp < CAP1) bucket[bb * CAP1 + gp] = lbin[bb * BINCAP + ln];
            }
        }
        return;
    }
    if (b >= NBKT + NCOMBO) {
        // ---- weight prep for layer 2: 256 blocks x 256 threads = 65536 ----
        int pb = b - (NBKT + NCOMBO);
        if (pb == 0 && threadIdx.x < HID) pooled[threadIdx.x] = 0.0f;
        int idx = pb * 256 + threadIdx.x;
        int k = idx & 127;
        int col = (idx >> 7) & 127;
        int mat = idx >> 14;
        float w = (mat < 3) ? rel_w[(((size_t)(3 + mat)) * HID + k) * HID + col]
                            : lin_w[((size_t)(HID + k)) * HID + col];
        wbuf[(size_t)mat * HID * WT_STRIDE + col * WT_STRIDE + k] = f2bf(w);
        return;
    }
    // ---- encoder + layer-1 tables (one combo per block; threads<128 act) ----
    int c = b - NBKT;  // 0..399
    int zi = c >> 2;
    int t = c & 3;
    int j = threadIdx.x;
    bool act = j < HID;
    if (act) {
        float acc = b1[t * HID + j];
#pragma unroll 8
        for (int k = 0; k < FEAT; ++k)
            acc = fmaf(z_embed[zi * FEAT + k], w1[((size_t)t * FEAT + k) * HID + j], acc);
        h[j] = fmaxf(acc, 0.0f);
    }
    __syncthreads();
    if (act) {
        float acc2 = b2[t * HID + j];
#pragma unroll 8
        for (int k = 0; k < HID; ++k)
            acc2 = fmaf(h[k], w2[(size_t)t * HID * HID + k * HID + j], acc2);
        xrow[j] = acc2;
    }
    __syncthreads();
#pragma unroll 1
    for (int r = 0; r < N_REL; ++r) {
        if (act) {
            float a = 0.f;
            const float* W = rel_w + (size_t)r * HID * HID;  // layer 0
#pragma unroll 8
            for (int k = 0; k < HID; ++k) a = fmaf(xrow[k], W[k * HID + j], a);
            tmp[j] = a;
        }
        __syncthreads();
        if (j < 32) {  // pack 4 fp8 per uint
            int w0 = __builtin_amdgcn_cvt_pk_fp8_f32(tmp[4 * j], tmp[4 * j + 1], 0, false);
            w0 = __builtin_amdgcn_cvt_pk_fp8_f32(tmp[4 * j + 2], tmp[4 * j + 3], w0, true);
            ytab[(r * NCOMBO + c) * 32 + j] = (unsigned)w0;
        }
        __syncthreads();
    }
    if (act) {
        float a = lin_b[j];
#pragma unroll 8
        for (int k = 0; k < HID; ++k) a = fmaf(xrow[k], lin_w[k * HID + j], a);
        lintab[c * HID + j] = a;
    }
}

// ---------------------------------------------------------------------------
// Pass 2: RELATION-SORTED scatter into padded per-node buckets.
// Final payload word: src(16) | combo(src)(9)<<18. cnt3 = c0|c1<<8|c2<<16.
__global__ __launch_bounds__(256) void build2_kernel(const int* __restrict__ bcnt,
                                                     const int* __restrict__ bucket,
                                                     const unsigned short* __restrict__ combo,
                                                     int* __restrict__ cnt3,
                                                     int* __restrict__ payload) {
    __shared__ int lcnt[256 * 3];
    for (int i = threadIdx.x; i < 768; i += 256) lcnt[i] = 0;
    __syncthreads();
    int b = blockIdx.x;
    int n0 = b << 8;
    int cb = min(bcnt[b], CAP1);
    const int* bk = bucket + b * CAP1;
    for (int i = threadIdx.x; i < cb; i += 256) {
        int v = bk[i];
        atomicAdd(&lcnt[((v >> 18) & 255) * 3 + ((v >> 16) & 3)], 1);
    }
    __syncthreads();
    int t = threadIdx.x;
    int c0 = min(lcnt[t * 3 + 0], CAP);
    int c1 = min(lcnt[t * 3 + 1], CAP - c0);
    int c2 = min(lcnt[t * 3 + 2], CAP - c0 - c1);
    __syncthreads();
    lcnt[t * 3 + 0] = 0;
    lcnt[t * 3 + 1] = c0;
    lcnt[t * 3 + 2] = c0 + c1;
    int node = n0 + t;
    if (node < N_NODES) cnt3[node] = c0 | (c1 << 8) | (c2 << 16);
    __syncthreads();
    for (int i = threadIdx.x; i < cb; i += 256) {
        int v = bk[i];
        int dl = (v >> 18) & 255;
        int r = (v >> 16) & 3;
        int sc = v & 0xffff;
        int pos = atomicAdd(&lcnt[dl * 3 + r], 1);
        if (pos < CAP)
            payload[((n0 + dl) << 6) + pos] = sc | ((int)combo[sc] << 18);
    }
}

// ---------------------------------------------------------------------------
// LAYER 1 fused: branch-free fp8 segment gather from ytab + lintab + LN.
// Emits xf8 (fp8, plain slot order: slot = k>>3). R8 verbatim.
__global__ __launch_bounds__(256) void gather_ln1_kernel(
    const int* __restrict__ cnt3, const int* __restrict__ payload,
    const uint2* __restrict__ ytab8, const float* __restrict__ lintab,
    const unsigned short* __restrict__ combo, const float* __restrict__ lng,
    const float* __restrict__ lnb, uint2* __restrict__ xf8) {
    int tid = blockIdx.x * 256 + threadIdx.x;
    int node = tid >> 4;  // 3125 blocks exact
    int l16 = tid & 15;
    int c3 = cnt3[node];
    int c0 = c3 & 255, c1 = (c3 >> 8) & 255, c2 = (c3 >> 16) & 255;
    int tot = c0 + c1 + c2;
    float inv = 1.0f / (float)max(tot, 1);
    const int* pl = payload + (node << 6);
    float a[8] = {};
    int e = 0;
#pragma unroll 1
    for (int r = 0; r < 3; ++r) {
        int e1 = (r == 0) ? c0 : (r == 1) ? c0 + c1 : tot;
        int base = (r * NCOMBO) << 4;
        for (; e + 4 <= e1; e += 4) {
            int pA = pl[e], pB = pl[e + 1], pC = pl[e + 2], pD = pl[e + 3];
            uint2 vA = ytab8[base + ((pA >> 18) << 4) + l16];
            uint2 vB = ytab8[base + ((pB >> 18) << 4) + l16];
            uint2 vC = ytab8[base + ((pC >> 18) << 4) + l16];
            uint2 vD = ytab8[base + ((pD >> 18) << 4) + l16];
            acc8_fp8(a, vA);
            acc8_fp8(a, vB);
            acc8_fp8(a, vC);
            acc8_fp8(a, vD);
        }
        if (e + 2 <= e1) {
            int pA = pl[e], pB = pl[e + 1];
            uint2 vA = ytab8[base + ((pA >> 18) << 4) + l16];
            uint2 vB = ytab8[base + ((pB >> 18) << 4) + l16];
            acc8_fp8(a, vA);
            acc8_fp8(a, vB);
            e += 2;
        }
        if (e < e1) {
            int p = pl[e]; ++e;
            acc8_fp8(a, ytab8[base + ((p >> 18) << 4) + l16]);
        }
    }
    const float* lrow = lintab + (int)combo[node] * HID + l16 * 8;
    float v[8], s = 0.f, q = 0.f;
#pragma unroll
    for (int j = 0; j < 8; ++j) {
        v[j] = fmaf(a[j], inv, lrow[j]);
        s += v[j];
        q += v[j] * v[j];
    }
#pragma unroll
    for (int mk = 1; mk < 16; mk <<= 1) {
        s += __shfl_xor(s, mk);
        q += __shfl_xor(q, mk);
    }
    float mu = s * (1.0f / HID);
    float rstd = rsqrtf(q * (1.0f / HID) - mu * mu + LN_EPS);
    const float* g8 = lng + l16 * 8;
    const float* b8 = lnb + l16 * 8;
    float o[8];
#pragma unroll
    for (int j = 0; j < 8; ++j) o[j] = (v[j] - mu) * rstd * g8[j] + b8[j];
    int lo = 0, hi = 0;
    lo = __builtin_amdgcn_cvt_pk_fp8_f32(o[0], o[1], lo, false);
    lo = __builtin_amdgcn_cvt_pk_fp8_f32(o[2], o[3], lo, true);
    hi = __builtin_amdgcn_cvt_pk_fp8_f32(o[4], o[5], hi, false);
    hi = __builtin_amdgcn_cvt_pk_fp8_f32(o[6], o[7], hi, true);
    xf8[(node << 4) + l16] = make_uint2((unsigned)lo, (unsigned)hi);
}

// ---------------------------------------------------------------------------
// LAYER 2 gather over fp8 rows (8B/lane): branch-free segments, fp32 accum,
// fp8 s_r stores (plain slot order). R8 verbatim.
__global__ __launch_bounds__(256) void gather3_kernel(const int* __restrict__ cnt3,
                                                      const int* __restrict__ payload,
                                                      const uint2* __restrict__ xf8,
                                                      uint2* __restrict__ s0,
                                                      uint2* __restrict__ s1,
                                                      uint2* __restrict__ s2) {
    int tid = blockIdx.x * 256 + threadIdx.x;
    int node = tid >> 4;
    int l16 = tid & 15;
    int c3 = cnt3[node];
    int c0 = c3 & 255, c1 = (c3 >> 8) & 255, c2 = (c3 >> 16) & 255;
    int tot = c0 + c1 + c2;
    float inv = 1.0f / (float)max(tot, 1);
    const int* pl = payload + (node << 6);
    int o = node * 16 + l16;
    int e = 0;
#pragma unroll 1
    for (int r = 0; r < 3; ++r) {
        int e1 = (r == 0) ? c0 : (r == 1) ? c0 + c1 : tot;
        float a[8] = {};
        for (; e + 4 <= e1; e += 4) {
            int pA = pl[e], pB = pl[e + 1], pC = pl[e + 2], pD = pl[e + 3];
            uint2 vA = xf8[((pA & 0xffff) << 4) + l16];
            uint2 vB = xf8[((pB & 0xffff) << 4) + l16];
            uint2 vC = xf8[((pC & 0xffff) << 4) + l16];
            uint2 vD = xf8[((pD & 0xffff) << 4) + l16];
            acc8_fp8(a, vA);
            acc8_fp8(a, vB);
            acc8_fp8(a, vC);
            acc8_fp8(a, vD);
        }
        if (e + 2 <= e1) {
            int pA = pl[e], pB = pl[e + 1];
            uint2 vA = xf8[((pA & 0xffff) << 4) + l16];
            uint2 vB = xf8[((pB & 0xffff) << 4) + l16];
            acc8_fp8(a, vA);
            acc8_fp8(a, vB);
            e += 2;
        }
        if (e < e1) {
            int p = pl[e]; ++e;
            acc8_fp8(a, xf8[((p & 0xffff) << 4) + l16]);
        }
        int lo = 0, hi = 0;
        lo = __builtin_amdgcn_cvt_pk_fp8_f32(a[0] * inv, a[1] * inv, lo, false);
        lo = __builtin_amdgcn_cvt_pk_fp8_f32(a[2] * inv, a[3] * inv, lo, true);
        hi = __builtin_amdgcn_cvt_pk_fp8_f32(a[4] * inv, a[5] * inv, hi, false);
        hi = __builtin_amdgcn_cvt_pk_fp8_f32(a[6] * inv, a[7] * inv, hi, true);
        uint2 w = make_uint2((unsigned)lo, (unsigned)hi);
        if (r == 0) s0[o] = w;
        else if (r == 1) s1[o] = w;
        else s2[o] = w;
    }
}

// ---------------------------------------------------------------------------
// Layer-2 fused GEMM+LN+pool. R10/R11: 16x16x32 MFMA, 16-node groups.
//  - 3125 groups = 50000/16 exactly -> ALL 2048 waves active (vs 1563).
//  - fp8 A: ALL 4 mats prefetch = 16 uint2 = 32 VGPR; acc = 8 f32x4 = 32.
//    Fits the 128-VGPR cap -> 16 loads in flight per wave, issued BEFORE
//    the Wt-staging barrier (fully hidden). Group 2's loads issue after
//    the MFMAs, hidden under group 1's epilogue.
//  - Fragment maps: A row=c16, k=kk*32+kg*8+j -> slot kk*4+kg;
//    B col=tile*16+c16, same k; C/D col=lane&15, row=(lane>>4)*4+reg [m89].
__global__ __launch_bounds__(512) void fused_layer_kernel(
    const uint2* __restrict__ s0, const uint2* __restrict__ s1,
    const uint2* __restrict__ s2, const uint2* __restrict__ xf8,
    const uint4* __restrict__ wbuf, const float* __restrict__ lb,
    const float* __restrict__ lng, const float* __restrict__ lnb,
    float* __restrict__ pooled, const float* __restrict__ reg_w,
    const float* __restrict__ reg_b, float* __restrict__ out,
    int* __restrict__ done) {
    __shared__ __align__(16) unsigned short Wt[4 * HID * WT_STRIDE];  // 139264 B
    __shared__ float csh[3 * HID];
    __shared__ float pooled_sh[HID];
    __shared__ int lastFlag;

    int wave = threadIdx.x >> 6;
    int lane = threadIdx.x & 63;
    int c16 = lane & 15;   // A row / C col-within-tile
    int kg = lane >> 4;    // k-octet group (0..3)

    int g0 = wave * gridDim.x + blockIdx.x;   // 0..2047, all < NG16: active
    uint2 buf[16];  // [mat*4 + kk], all compile-time indexed

#define LDALL(g)                                                               \
    {                                                                          \
        int _b = ((g) * 16 + c16) * 16 + kg;  /* uint2 index: node*16 + slot */\
        _Pragma("unroll")                                                      \
        for (int kk = 0; kk < 4; ++kk) {                                       \
            buf[0 * 4 + kk] = s0[_b + kk * 4];                                 \
            buf[1 * 4 + kk] = s1[_b + kk * 4];                                 \
            buf[2 * 4 + kk] = s2[_b + kk * 4];                                 \
            buf[3 * 4 + kk] = xf8[_b + kk * 4];                                \
        }                                                                      \
    }

    LDALL(g0);  // 16 x 8B loads in flight, hidden under the 139 KB Wt stage

    if (threadIdx.x < HID) {
        pooled_sh[threadIdx.x] = 0.0f;
        csh[threadIdx.x] = lb[threadIdx.x];
        csh[HID + threadIdx.x] = lng[threadIdx.x];
        csh[2 * HID + threadIdx.x] = lnb[threadIdx.x];
    }
    uint4* wt4 = (uint4*)Wt;
#pragma unroll
    for (int i = 0; i < 17; ++i)
        wt4[i * 512 + threadIdx.x] = wbuf[i * 512 + threadIdx.x];
    __syncthreads();

    float pacc[8] = {};
    const unsigned short* wlane = Wt + c16 * WT_STRIDE + kg * 8;

#define COMPUTE(accv)                                                          \
    _Pragma("unroll")                                                          \
    for (int mat = 0; mat < 4; ++mat) {                                        \
        const unsigned short* wm = wlane + mat * (HID * WT_STRIDE);            \
        _Pragma("unroll")                                                      \
        for (int kk = 0; kk < 4; ++kk) {                                       \
            bf16x8 afr = f8_to_bf16x8(buf[mat * 4 + kk]);                      \
            _Pragma("unroll")                                                  \
            for (int tile = 0; tile < 8; ++tile) {                             \
                bf16x8 bfr = *(const bf16x8*)(wm + tile * 16 * WT_STRIDE + kk * 32); \
                accv[tile] = __builtin_amdgcn_mfma_f32_16x16x32_bf16(          \
                    afr, bfr, accv[tile], 0, 0, 0);                            \
            }                                                                  \
        }                                                                      \
    }

#define EPILOGUE(accv)                                                         \
    _Pragma("unroll")                                                          \
    for (int reg = 0; reg < 4; ++reg) {                                        \
        float v[8], s = 0.f, q = 0.f;                                          \
        _Pragma("unroll")                                                      \
        for (int tile = 0; tile < 8; ++tile) {                                 \
            v[tile] = accv[tile][reg] + csh[tile * 16 + c16];                  \
            s += v[tile];                                                      \
            q += v[tile] * v[tile];                                            \
        }                                                                      \
        _Pragma("unroll")                                                      \
        for (int mk = 1; mk < 16; mk <<= 1) {                                  \
            s += __shfl_xor(s, mk);                                            \
            q += __shfl_xor(q, mk);                                            \
        }                                                                      \
        float mu = s * (1.0f / HID);                                           \
        float rstd = rsqrtf(q * (1.0f / HID) - mu * mu + LN_EPS);              \
        _Pragma("unroll")                                                      \
        for (int tile = 0; tile < 8; ++tile) {                                 \
            int col = tile * 16 + c16;                                         \
            pacc[tile] += (v[tile] - mu) * rstd * csh[HID + col] + csh[2 * HID + col]; \
        }                                                                      \
    }

    {
        f32x4 acc[8];
#pragma unroll
        for (int t = 0; t < 8; ++t) acc[t] = (f32x4){0.f, 0.f, 0.f, 0.f};
        COMPUTE(acc);
        int g1 = g0 + 2048;
        bool has2 = g1 < NG16;
        if (has2) LDALL(g1);   // issue under the epilogue's shfl/VALU
        EPILOGUE(acc);
        if (has2) {
            f32x4 acc2[8];
#pragma unroll
            for (int t = 0; t < 8; ++t) acc2[t] = (f32x4){0.f, 0.f, 0.f, 0.f};
            COMPUTE(acc2);
            EPILOGUE(acc2);
        }
    }
#undef LDALL
#undef COMPUTE
#undef EPILOGUE

    // pool: lane holds cols {tile*16 + c16}; reduce across kg via shfl
#pragma unroll
    for (int tile = 0; tile < 8; ++tile) {
        float t = pacc[tile] + __shfl_xor(pacc[tile], 16);
        t += __shfl_xor(t, 32);
        if (kg == 0) atomicAdd(&pooled_sh[tile * 16 + c16], t);
    }
    __syncthreads();
    if (threadIdx.x < HID) atomicAdd(&pooled[threadIdx.x], pooled_sh[threadIdx.x]);

    // ---- folded final reduction (last block) ----
    __threadfence();
    __syncthreads();
    if (threadIdx.x == 0)
        lastFlag = (atomicAdd(done, 1) == (int)gridDim.x - 1);
    __syncthreads();
    if (lastFlag && threadIdx.x < 64) {
        int l = threadIdx.x;
        // atomic fetch-add(0) reads take the same coherent path as the writes
        float s = atomicAdd(&pooled[l], 0.0f) * reg_w[l] +
                  atomicAdd(&pooled[64 + l], 0.0f) * reg_w[64 + l];
#pragma unroll
        for (int o = 32; o; o >>= 1) s += __shfl_down(s, o);
        if (l == 0) out[0] = s * (1.0f / N_NODES) + reg_b[0];
    }
}

// ---------------------------------------------------------------------------
extern "C" void kernel_launch(void* const* d_in, const int* in_sizes, int n_in,
                              void* d_out, int out_size, void* d_ws, size_t ws_size,
                              hipStream_t stream) {
    const int* z = (const int*)d_in[0];
    const int* nt = (const int*)d_in[1];
    const int* ei = (const int*)d_in[2];
    const int* et = (const int*)d_in[3];
    const float* z_embed = (const float*)d_in[4];
    const float* enc_w1 = (const float*)d_in[5];
    const float* enc_b1 = (const float*)d_in[6];
    const float* enc_w2 = (const float*)d_in[7];
    const float* enc_b2 = (const float*)d_in[8];
    const float* lin_w = (const float*)d_in[9];
    const float* lin_b = (const float*)d_in[10];
    const float* rel_w = (const float*)d_in[11];
    const float* ln_g = (const float*)d_in[12];
    const float* ln_b = (const float*)d_in[13];
    const float* reg_w = (const float*)d_in[14];
    const float* reg_b = (const float*)d_in[15];
    float* out = (float*)d_out;

    const size_t NHf8 = (size_t)NROWS * HID;  // bytes per fp8 feature plane
    char* p = (char*)d_ws;
    uint2* xf8 = (uint2*)p;                     p += NHf8;   // 6.4 MB
    uint2* s0 = (uint2*)p;                      p += NHf8;   // fp8 means
    uint2* s1 = (uint2*)p;                      p += NHf8;
    uint2* s2 = (uint2*)p;                      p += NHf8;
    unsigned short* wbuf = (unsigned short*)p;  p += (size_t)4 * HID * WT_STRIDE * 2;
    unsigned int* ytab = (unsigned int*)p;      p += (size_t)N_REL * NCOMBO * HID;  // fp8
    float* lintab = (float*)p;                  p += NCOMBO * HID * 4;
    unsigned short* combo = (unsigned short*)p; p += N_NODES * 2;
    float* pooled = (float*)p;                  p += HID * 4;
    int* cnt3 = (int*)p;                        p += N_NODES * 4;
    int* bcnt = (int*)p;                        p += NBKT * 4;
    int* done = (int*)p;                        p += 4;        // adjacent to bcnt
    int* bucket = (int*)p;                      p += (size_t)NBKT * CAP1 * 4;
    int* payload = (int*)p;                     p += (size_t)N_NODES * CAP * 4;

    const int* src = ei;
    const int* dst = ei + N_EDGES;

    hipMemsetAsync(bcnt, 0, (NBKT + 1) * sizeof(int), stream);  // bcnt + done

    // front-end: edge binning || encoder tables || weight prep (one dispatch)
    build_tables_kernel<<<NBKT + NCOMBO + 256, 256, 0, stream>>>(
        src, dst, et, z, nt, z_embed, enc_w1, enc_b1, enc_w2, enc_b2,
        rel_w, lin_w, lin_b, combo, bcnt, bucket, ytab, lintab, wbuf, pooled);

    build2_kernel<<<NBKT, 256, 0, stream>>>(bcnt, bucket, combo, cnt3, payload);

    // layer 1: fused fp8 table-gather + lin + LN -> xf8 (fp8)
    gather_ln1_kernel<<<3125, 256, 0, stream>>>(cnt3, payload, (const uint2*)ytab, lintab,
                                                combo, ln_g, ln_b, xf8);
    // layer 2: fp8 gather -> fp8 means; 16x16 MFMA fused layer
    gather3_kernel<<<3125, 256, 0, stream>>>(cnt3, payload, xf8, s0, s1, s2);
    fused_layer_kernel<<<256, 512, 0, stream>>>(
        s0, s1, s2, xf8, (const uint4*)wbuf, lin_b + HID, ln_g + HID, ln_b + HID,
        pooled, reg_w, reg_b, out, done);
}

// Round 12
// 227.657 us; speedup vs baseline: 1.4547x; 1.0231x over previous
//
#include <hip/hip_runtime.h>

#define N_NODES 50000
#define N_EDGES 800000
#define FEAT 64
#define HID 128
#define N_TYPES 4
#define N_REL 3
#define N_LAYERS 2
#define LN_EPS 1e-5f
#define NROWS 50016   // 50000 padded to 32
#define NG16 3125     // 16-node groups: 3125 x 16 = 50000 exactly
#define CAP 64        // per-dst bucket capacity
#define NBKT 196      // coarse buckets: dst>>8
#define CAP1 4608     // coarse bucket capacity (mean 4082, +8 sigma)
#define EPB 4096      // edges per bin1 block
#define BINCAP 56     // per-block per-bin LDS capacity (mean 20.9, +7.7 sigma)
#define NCOMBO 400    // 100 z-values x 4 types
#define WT_STRIDE 136

typedef __attribute__((ext_vector_type(8))) short bf16x8;
typedef __attribute__((ext_vector_type(4))) float f32x4;
typedef __attribute__((ext_vector_type(2))) float f32x2;

static __device__ inline unsigned short f2bf(float f) {
    unsigned int u = __float_as_uint(f);
    return (unsigned short)((u + 0x7fffu + ((u >> 16) & 1u)) >> 16);
}
static __device__ inline unsigned int packbf2(float lo, float hi) {
    return (unsigned int)f2bf(lo) | ((unsigned int)f2bf(hi) << 16);
}

// decode 8 fp8-e4m3 (uint2) -> accumulate into a[0..7]
static __device__ inline void acc8_fp8(float* a, uint2 w) {
    f32x2 d0 = __builtin_amdgcn_cvt_pk_f32_fp8((int)w.x, false);
    f32x2 d1 = __builtin_amdgcn_cvt_pk_f32_fp8((int)w.x, true);
    f32x2 d2 = __builtin_amdgcn_cvt_pk_f32_fp8((int)w.y, false);
    f32x2 d3 = __builtin_amdgcn_cvt_pk_f32_fp8((int)w.y, true);
    a[0] += d0[0]; a[1] += d0[1]; a[2] += d1[0]; a[3] += d1[1];
    a[4] += d2[0]; a[5] += d2[1]; a[6] += d3[0]; a[7] += d3[1];
}
// decode 8 fp8-e4m3 (uint2) -> d[0..7]
static __device__ inline void dec8_fp8(float* d, uint2 w) {
    f32x2 d0 = __builtin_amdgcn_cvt_pk_f32_fp8((int)w.x, false);
    f32x2 d1 = __builtin_amdgcn_cvt_pk_f32_fp8((int)w.x, true);
    f32x2 d2 = __builtin_amdgcn_cvt_pk_f32_fp8((int)w.y, false);
    f32x2 d3 = __builtin_amdgcn_cvt_pk_f32_fp8((int)w.y, true);
    d[0] = d0[0]; d[1] = d0[1]; d[2] = d1[0]; d[3] = d1[1];
    d[4] = d2[0]; d[5] = d2[1]; d[6] = d3[0]; d[7] = d3[1];
}
// decode 8 fp8-e4m3 (uint2) -> bf16x8 (lossless: e4m3 values are exact in bf16)
static __device__ inline bf16x8 f8_to_bf16x8(uint2 w) {
    f32x2 d0 = __builtin_amdgcn_cvt_pk_f32_fp8((int)w.x, false);
    f32x2 d1 = __builtin_amdgcn_cvt_pk_f32_fp8((int)w.x, true);
    f32x2 d2 = __builtin_amdgcn_cvt_pk_f32_fp8((int)w.y, false);
    f32x2 d3 = __builtin_amdgcn_cvt_pk_f32_fp8((int)w.y, true);
    union { bf16x8 v; unsigned int u[4]; } r;
    r.u[0] = packbf2(d0[0], d0[1]);
    r.u[1] = packbf2(d1[0], d1[1]);
    r.u[2] = packbf2(d2[0], d2[1]);
    r.u[3] = packbf2(d3[0], d3[1]);
    return r.v;
}

// ---------------------------------------------------------------------------
// MERGED front-end: blocks [0,196) = edge binning (+combo), [196,596) =
// encoder/layer-1 tables, [596,852) = layer-2 weight prep + pooled zero.
__global__ __launch_bounds__(256) void build_tables_kernel(
    const int* __restrict__ src, const int* __restrict__ dst,
    const int* __restrict__ et, const int* __restrict__ z,
    const int* __restrict__ nt,
    const float* __restrict__ z_embed, const float* __restrict__ w1,
    const float* __restrict__ b1, const float* __restrict__ w2,
    const float* __restrict__ b2, const float* __restrict__ rel_w,
    const float* __restrict__ lin_w, const float* __restrict__ lin_b,
    unsigned short* __restrict__ combo, int* __restrict__ bcnt,
    int* __restrict__ bucket, unsigned int* __restrict__ ytab,
    float* __restrict__ lintab, unsigned short* __restrict__ wbuf,
    float* __restrict__ pooled) {
    __shared__ int lbin[NBKT * BINCAP];  // 43.9 KB (bin1 branch only)
    __shared__ int lcnt[NBKT];
    __shared__ int lbase[NBKT];
    __shared__ float h[HID];             // encoder branch only
    __shared__ float xrow[HID];
    __shared__ float tmp[HID];

    int b = blockIdx.x;
    if (b < NBKT) {
        // ---- bin1: bin edges by dst>>8. Packed: src|et<<16|(dst&255)<<18 ----
        int ci = b * 256 + threadIdx.x;
        if (ci < N_NODES) combo[ci] = (unsigned short)(z[ci] * 4 + nt[ci]);
        for (int i = threadIdx.x; i < NBKT; i += 256) lcnt[i] = 0;
        __syncthreads();
        int base = b * EPB;
#pragma unroll
        for (int i = 0; i < EPB / 256; ++i) {
            int e = base + i * 256 + threadIdx.x;
            if (e < N_EDGES) {
                int d = dst[e];
                int bk = d >> 8;
                int v = src[e] | (et[e] << 16) | ((d & 255) << 18);
                int pos = atomicAdd(&lcnt[bk], 1);
                if (pos < BINCAP) lbin[bk * BINCAP + pos] = v;
            }
        }
        __syncthreads();
        if (threadIdx.x < NBKT) {
            int c = min(lcnt[threadIdx.x], BINCAP);
            lcnt[threadIdx.x] = c;
            lbase[threadIdx.x] = atomicAdd(&bcnt[threadIdx.x], c);
        }
        __syncthreads();
        int wv = threadIdx.x >> 6, ln = threadIdx.x & 63;
        for (int bb = wv; bb < NBKT; bb += 4) {
            int c = lcnt[bb];
            if (ln < c) {
                int gp = lbase[bb] + ln;
                if (gp < CAP1) bucket[bb * CAP1 + gp] = lbin[bb * BINCAP + ln];
            }
        }
        return;
    }
    if (b >= NBKT + NCOMBO) {
        // ---- weight prep for layer 2: 256 blocks x 256 threads = 65536 ----
        int pb = b - (NBKT + NCOMBO);
        if (pb == 0 && threadIdx.x < HID) pooled[threadIdx.x] = 0.0f;
        int idx = pb * 256 + threadIdx.x;
        int k = idx & 127;
        int col = (idx >> 7) & 127;
        int mat = idx >> 14;
        float w = (mat < 3) ? rel_w[(((size_t)(3 + mat)) * HID + k) * HID + col]
                            : lin_w[((size_t)(HID + k)) * HID + col];
        wbuf[(size_t)mat * HID * WT_STRIDE + col * WT_STRIDE + k] = f2bf(w);
        return;
    }
    // ---- encoder + layer-1 tables (one combo per block; threads<128 act) ----
    int c = b - NBKT;  // 0..399
    int zi = c >> 2;
    int t = c & 3;
    int j = threadIdx.x;
    bool act = j < HID;
    if (act) {
        float acc = b1[t * HID + j];
#pragma unroll 8
        for (int k = 0; k < FEAT; ++k)
            acc = fmaf(z_embed[zi * FEAT + k], w1[((size_t)t * FEAT + k) * HID + j], acc);
        h[j] = fmaxf(acc, 0.0f);
    }
    __syncthreads();
    if (act) {
        float acc2 = b2[t * HID + j];
#pragma unroll 8
        for (int k = 0; k < HID; ++k)
            acc2 = fmaf(h[k], w2[(size_t)t * HID * HID + k * HID + j], acc2);
        xrow[j] = acc2;
    }
    __syncthreads();
#pragma unroll 1
    for (int r = 0; r < N_REL; ++r) {
        if (act) {
            float a = 0.f;
            const float* W = rel_w + (size_t)r * HID * HID;  // layer 0
#pragma unroll 8
            for (int k = 0; k < HID; ++k) a = fmaf(xrow[k], W[k * HID + j], a);
            tmp[j] = a;
        }
        __syncthreads();
        if (j < 32) {  // pack 4 fp8 per uint
            int w0 = __builtin_amdgcn_cvt_pk_fp8_f32(tmp[4 * j], tmp[4 * j + 1], 0, false);
            w0 = __builtin_amdgcn_cvt_pk_fp8_f32(tmp[4 * j + 2], tmp[4 * j + 3], w0, true);
            ytab[(r * NCOMBO + c) * 32 + j] = (unsigned)w0;
        }
        __syncthreads();
    }
    if (act) {
        float a = lin_b[j];
#pragma unroll 8
        for (int k = 0; k < HID; ++k) a = fmaf(xrow[k], lin_w[k * HID + j], a);
        lintab[c * HID + j] = a;
    }
}

// ---------------------------------------------------------------------------
// Pass 2: RELATION-SORTED scatter into padded per-node buckets.
// Final payload word: src(16) | combo(src)(9)<<18. cnt3 = c0|c1<<8|c2<<16.
__global__ __launch_bounds__(256) void build2_kernel(const int* __restrict__ bcnt,
                                                     const int* __restrict__ bucket,
                                                     const unsigned short* __restrict__ combo,
                                                     int* __restrict__ cnt3,
                                                     int* __restrict__ payload) {
    __shared__ int lcnt[256 * 3];
    for (int i = threadIdx.x; i < 768; i += 256) lcnt[i] = 0;
    __syncthreads();
    int b = blockIdx.x;
    int n0 = b << 8;
    int cb = min(bcnt[b], CAP1);
    const int* bk = bucket + b * CAP1;
    for (int i = threadIdx.x; i < cb; i += 256) {
        int v = bk[i];
        atomicAdd(&lcnt[((v >> 18) & 255) * 3 + ((v >> 16) & 3)], 1);
    }
    __syncthreads();
    int t = threadIdx.x;
    int c0 = min(lcnt[t * 3 + 0], CAP);
    int c1 = min(lcnt[t * 3 + 1], CAP - c0);
    int c2 = min(lcnt[t * 3 + 2], CAP - c0 - c1);
    __syncthreads();
    lcnt[t * 3 + 0] = 0;
    lcnt[t * 3 + 1] = c0;
    lcnt[t * 3 + 2] = c0 + c1;
    int node = n0 + t;
    if (node < N_NODES) cnt3[node] = c0 | (c1 << 8) | (c2 << 16);
    __syncthreads();
    for (int i = threadIdx.x; i < cb; i += 256) {
        int v = bk[i];
        int dl = (v >> 18) & 255;
        int r = (v >> 16) & 3;
        int sc = v & 0xffff;
        int pos = atomicAdd(&lcnt[dl * 3 + r], 1);
        if (pos < CAP)
            payload[((n0 + dl) << 6) + pos] = sc | ((int)combo[sc] << 18);
    }
}

// ---------------------------------------------------------------------------
// LAYER 1 fused: fp8 segment gather from ytab + lintab + LN -> xf8.
// R12: FLAT edge loop, 8-deep windows. Relation base chosen branchlessly
// (payload is relation-sorted, so flat order == segment order: bit-identical
// accumulation). 8 independent table loads in flight per window vs the old
// per-segment 4-unroll that rarely filled (mean segment length 5.3).
__global__ __launch_bounds__(256) void gather_ln1_kernel(
    const int* __restrict__ cnt3, const int* __restrict__ payload,
    const uint2* __restrict__ ytab8, const float* __restrict__ lintab,
    const unsigned short* __restrict__ combo, const float* __restrict__ lng,
    const float* __restrict__ lnb, uint2* __restrict__ xf8) {
    int tid = blockIdx.x * 256 + threadIdx.x;
    int node = tid >> 4;  // 3125 blocks exact
    int l16 = tid & 15;
    int c3 = cnt3[node];
    int c0 = c3 & 255, c1 = (c3 >> 8) & 255, c2 = (c3 >> 16) & 255;
    int tot = c0 + c1 + c2;
    int c01 = c0 + c1;
    float inv = 1.0f / (float)max(tot, 1);
    const int* pl = payload + (node << 6);
    const int B1 = NCOMBO << 4, B2 = (2 * NCOMBO) << 4;
    float a[8] = {};
    int e = 0;
    for (; e + 8 <= tot; e += 8) {
        uint4 w0 = *(const uint4*)(pl + e);
        uint4 w1 = *(const uint4*)(pl + e + 4);
        int pp[8] = {(int)w0.x, (int)w0.y, (int)w0.z, (int)w0.w,
                     (int)w1.x, (int)w1.y, (int)w1.z, (int)w1.w};
        uint2 v[8];
#pragma unroll
        for (int j = 0; j < 8; ++j) {
            int ee = e + j;
            int base = (ee < c0) ? 0 : (ee < c01) ? B1 : B2;
            v[j] = ytab8[base + ((pp[j] >> 18) << 4) + l16];
        }
#pragma unroll
        for (int j = 0; j < 8; ++j) acc8_fp8(a, v[j]);
    }
    if (e + 4 <= tot) {
        uint4 w0 = *(const uint4*)(pl + e);
        int pp[4] = {(int)w0.x, (int)w0.y, (int)w0.z, (int)w0.w};
        uint2 v[4];
#pragma unroll
        for (int j = 0; j < 4; ++j) {
            int ee = e + j;
            int base = (ee < c0) ? 0 : (ee < c01) ? B1 : B2;
            v[j] = ytab8[base + ((pp[j] >> 18) << 4) + l16];
        }
#pragma unroll
        for (int j = 0; j < 4; ++j) acc8_fp8(a, v[j]);
        e += 4;
    }
    if (e + 2 <= tot) {
        uint2 w0 = *(const uint2*)(pl + e);
        int pp[2] = {(int)w0.x, (int)w0.y};
        uint2 v[2];
#pragma unroll
        for (int j = 0; j < 2; ++j) {
            int ee = e + j;
            int base = (ee < c0) ? 0 : (ee < c01) ? B1 : B2;
            v[j] = ytab8[base + ((pp[j] >> 18) << 4) + l16];
        }
        acc8_fp8(a, v[0]);
        acc8_fp8(a, v[1]);
        e += 2;
    }
    if (e < tot) {
        int p = pl[e];
        int base = (e < c0) ? 0 : (e < c01) ? B1 : B2;
        acc8_fp8(a, ytab8[base + ((p >> 18) << 4) + l16]);
    }
    const float* lrow = lintab + (int)combo[node] * HID + l16 * 8;
    float v[8], s = 0.f, q = 0.f;
#pragma unroll
    for (int j = 0; j < 8; ++j) {
        v[j] = fmaf(a[j], inv, lrow[j]);
        s += v[j];
        q += v[j] * v[j];
    }
#pragma unroll
    for (int mk = 1; mk < 16; mk <<= 1) {
        s += __shfl_xor(s, mk);
        q += __shfl_xor(q, mk);
    }
    float mu = s * (1.0f / HID);
    float rstd = rsqrtf(q * (1.0f / HID) - mu * mu + LN_EPS);
    const float* g8 = lng + l16 * 8;
    const float* b8 = lnb + l16 * 8;
    float o[8];
#pragma unroll
    for (int j = 0; j < 8; ++j) o[j] = (v[j] - mu) * rstd * g8[j] + b8[j];
    int lo = 0, hi = 0;
    lo = __builtin_amdgcn_cvt_pk_fp8_f32(o[0], o[1], lo, false);
    lo = __builtin_amdgcn_cvt_pk_fp8_f32(o[2], o[3], lo, true);
    hi = __builtin_amdgcn_cvt_pk_fp8_f32(o[4], o[5], hi, false);
    hi = __builtin_amdgcn_cvt_pk_fp8_f32(o[6], o[7], hi, true);
    xf8[(node << 4) + l16] = make_uint2((unsigned)lo, (unsigned)hi);
}

// ---------------------------------------------------------------------------
// LAYER 2 gather over fp8 rows. R12: FLAT edge loop, 8-deep windows, with
// THREE accumulators updated by 0/1-mask FMAs (relation select without
// segment loops). Masked adds contribute exact 0.0 -> bit-identical to the
// segmented version. ~3x VALU per edge but chip-wide VALU was 7% (free);
// buys 8 independent loads in flight per 16-lane group.
__global__ __launch_bounds__(256) void gather3_kernel(const int* __restrict__ cnt3,
                                                      const int* __restrict__ payload,
                                                      const uint2* __restrict__ xf8,
                                                      uint2* __restrict__ s0,
                                                      uint2* __restrict__ s1,
                                                      uint2* __restrict__ s2) {
    int tid = blockIdx.x * 256 + threadIdx.x;
    int node = tid >> 4;
    int l16 = tid & 15;
    int c3 = cnt3[node];
    int c0 = c3 & 255, c1 = (c3 >> 8) & 255, c2 = (c3 >> 16) & 255;
    int tot = c0 + c1 + c2;
    int c01 = c0 + c1;
    float inv = 1.0f / (float)max(tot, 1);
    const int* pl = payload + (node << 6);
    int o = node * 16 + l16;
    float a0[8] = {}, a1[8] = {}, a2[8] = {};
#define EDGE_ACC(j, ee, pv)                                                    \
    {                                                                          \
        float d[8];                                                            \
        dec8_fp8(d, pv);                                                       \
        float m0 = ((ee) < c0) ? 1.f : 0.f;                                    \
        float m1 = ((ee) >= c0 && (ee) < c01) ? 1.f : 0.f;                     \
        float m2 = ((ee) >= c01) ? 1.f : 0.f;                                  \
        _Pragma("unroll")                                                      \
        for (int q_ = 0; q_ < 8; ++q_) {                                       \
            a0[q_] = fmaf(m0, d[q_], a0[q_]);                                  \
            a1[q_] = fmaf(m1, d[q_], a1[q_]);                                  \
            a2[q_] = fmaf(m2, d[q_], a2[q_]);                                  \
        }                                                                      \
    }
    int e = 0;
    for (; e + 8 <= tot; e += 8) {
        uint4 w0 = *(const uint4*)(pl + e);
        uint4 w1 = *(const uint4*)(pl + e + 4);
        int pp[8] = {(int)w0.x, (int)w0.y, (int)w0.z, (int)w0.w,
                     (int)w1.x, (int)w1.y, (int)w1.z, (int)w1.w};
        uint2 v[8];
#pragma unroll
        for (int j = 0; j < 8; ++j)
            v[j] = xf8[((pp[j] & 0xffff) << 4) + l16];
#pragma unroll
        for (int j = 0; j < 8; ++j) EDGE_ACC(j, e + j, v[j]);
    }
    if (e + 4 <= tot) {
        uint4 w0 = *(const uint4*)(pl + e);
        int pp[4] = {(int)w0.x, (int)w0.y, (int)w0.z, (int)w0.w};
        uint2 v[4];
#pragma unroll
        for (int j = 0; j < 4; ++j)
            v[j] = xf8[((pp[j] & 0xffff) << 4) + l16];
#pragma unroll
        for (int j = 0; j < 4; ++j) EDGE_ACC(j, e + j, v[j]);
        e += 4;
    }
    if (e + 2 <= tot) {
        uint2 w0 = *(const uint2*)(pl + e);
        int pp[2] = {(int)w0.x, (int)w0.y};
        uint2 v[2];
        v[0] = xf8[((pp[0] & 0xffff) << 4) + l16];
        v[1] = xf8[((pp[1] & 0xffff) << 4) + l16];
        EDGE_ACC(0, e, v[0]);
        EDGE_ACC(1, e + 1, v[1]);
        e += 2;
    }
    if (e < tot) {
        int p = pl[e];
        uint2 v0 = xf8[((p & 0xffff) << 4) + l16];
        EDGE_ACC(0, e, v0);
    }
#undef EDGE_ACC
    {
        int lo = 0, hi = 0;
        lo = __builtin_amdgcn_cvt_pk_fp8_f32(a0[0] * inv, a0[1] * inv, lo, false);
        lo = __builtin_amdgcn_cvt_pk_fp8_f32(a0[2] * inv, a0[3] * inv, lo, true);
        hi = __builtin_amdgcn_cvt_pk_fp8_f32(a0[4] * inv, a0[5] * inv, hi, false);
        hi = __builtin_amdgcn_cvt_pk_fp8_f32(a0[6] * inv, a0[7] * inv, hi, true);
        s0[o] = make_uint2((unsigned)lo, (unsigned)hi);
    }
    {
        int lo = 0, hi = 0;
        lo = __builtin_amdgcn_cvt_pk_fp8_f32(a1[0] * inv, a1[1] * inv, lo, false);
        lo = __builtin_amdgcn_cvt_pk_fp8_f32(a1[2] * inv, a1[3] * inv, lo, true);
        hi = __builtin_amdgcn_cvt_pk_fp8_f32(a1[4] * inv, a1[5] * inv, hi, false);
        hi = __builtin_amdgcn_cvt_pk_fp8_f32(a1[6] * inv, a1[7] * inv, hi, true);
        s1[o] = make_uint2((unsigned)lo, (unsigned)hi);
    }
    {
        int lo = 0, hi = 0;
        lo = __builtin_amdgcn_cvt_pk_fp8_f32(a2[0] * inv, a2[1] * inv, lo, false);
        lo = __builtin_amdgcn_cvt_pk_fp8_f32(a2[2] * inv, a2[3] * inv, lo, true);
        hi = __builtin_amdgcn_cvt_pk_fp8_f32(a2[4] * inv, a2[5] * inv, hi, false);
        hi = __builtin_amdgcn_cvt_pk_fp8_f32(a2[6] * inv, a2[7] * inv, hi, true);
        s2[o] = make_uint2((unsigned)lo, (unsigned)hi);
    }
}

// ---------------------------------------------------------------------------
// Layer-2 fused GEMM+LN+pool. R11 structure (best component: 49.6 µs,
// VGPR 108, no spill): 16x16x32 MFMA, 16-node groups, all-2048-waves,
// full 4-mat fp8 prefetch issued before the Wt-staging barrier.
__global__ __launch_bounds__(512) void fused_layer_kernel(
    const uint2* __restrict__ s0, const uint2* __restrict__ s1,
    const uint2* __restrict__ s2, const uint2* __restrict__ xf8,
    const uint4* __restrict__ wbuf, const float* __restrict__ lb,
    const float* __restrict__ lng, const float* __restrict__ lnb,
    float* __restrict__ pooled, const float* __restrict__ reg_w,
    const float* __restrict__ reg_b, float* __restrict__ out,
    int* __restrict__ done) {
    __shared__ __align__(16) unsigned short Wt[4 * HID * WT_STRIDE];  // 139264 B
    __shared__ float csh[3 * HID];
    __shared__ float pooled_sh[HID];
    __shared__ int lastFlag;

    int wave = threadIdx.x >> 6;
    int lane = threadIdx.x & 63;
    int c16 = lane & 15;   // A row / C col-within-tile
    int kg = lane >> 4;    // k-octet group (0..3)

    int g0 = wave * gridDim.x + blockIdx.x;   // 0..2047, all < NG16: active
    uint2 buf[16];  // [mat*4 + kk], all compile-time indexed

#define LDALL(g)                                                               \
    {                                                                          \
        int _b = ((g) * 16 + c16) * 16 + kg;  /* uint2 index: node*16 + slot */\
        _Pragma("unroll")                                                      \
        for (int kk = 0; kk < 4; ++kk) {                                       \
            buf[0 * 4 + kk] = s0[_b + kk * 4];                                 \
            buf[1 * 4 + kk] = s1[_b + kk * 4];                                 \
            buf[2 * 4 + kk] = s2[_b + kk * 4];                                 \
            buf[3 * 4 + kk] = xf8[_b + kk * 4];                                \
        }                                                                      \
    }

    LDALL(g0);  // 16 x 8B loads in flight, hidden under the 139 KB Wt stage

    if (threadIdx.x < HID) {
        pooled_sh[threadIdx.x] = 0.0f;
        csh[threadIdx.x] = lb[threadIdx.x];
        csh[HID + threadIdx.x] = lng[threadIdx.x];
        csh[2 * HID + threadIdx.x] = lnb[threadIdx.x];
    }
    uint4* wt4 = (uint4*)Wt;
#pragma unroll
    for (int i = 0; i < 17; ++i)
        wt4[i * 512 + threadIdx.x] = wbuf[i * 512 + threadIdx.x];
    __syncthreads();

    float pacc[8] = {};
    const unsigned short* wlane = Wt + c16 * WT_STRIDE + kg * 8;

#define COMPUTE(accv)                                                          \
    _Pragma("unroll")                                                          \
    for (int mat = 0; mat < 4; ++mat) {                                        \
        const unsigned short* wm = wlane + mat * (HID * WT_STRIDE);            \
        _Pragma("unroll")                                                      \
        for (int kk = 0; kk < 4; ++kk) {                                       \
            bf16x8 afr = f8_to_bf16x8(buf[mat * 4 + kk]);                      \
            _Pragma("unroll")                                                  \
            for (int tile = 0; tile < 8; ++tile) {                             \
                bf16x8 bfr = *(const bf16x8*)(wm + tile * 16 * WT_STRIDE + kk * 32); \
                accv[tile] = __builtin_amdgcn_mfma_f32_16x16x32_bf16(          \
                    afr, bfr, accv[tile], 0, 0, 0);                            \
            }                                                                  \
        }                                                                      \
    }

#define EPILOGUE(accv)                                                         \
    _Pragma("unroll")                                                          \
    for (int reg = 0; reg < 4; ++reg) {                                        \
        float v[8], s = 0.f, q = 0.f;                                          \
        _Pragma("unroll")                                                      \
        for (int tile = 0; tile < 8; ++tile) {                                 \
            v[tile] = accv[tile][reg] + csh[tile * 16 + c16];                  \
            s += v[tile];                                                      \
            q += v[tile] * v[tile];                                            \
        }                                                                      \
        _Pragma("unroll")                                                      \
        for (int mk = 1; mk < 16; mk <<= 1) {                                  \
            s += __shfl_xor(s, mk);                                            \
            q += __shfl_xor(q, mk);                                            \
        }                                                                      \
        float mu = s * (1.0f / HID);                                           \
        float rstd = rsqrtf(q * (1.0f / HID) - mu * mu + LN_EPS);              \
        _Pragma("unroll")                                                      \
        for (int tile = 0; tile < 8; ++tile) {                                 \
            int col = tile * 16 + c16;                                         \
            pacc[tile] += (v[tile] - mu) * rstd * csh[HID + col] + csh[2 * HID + col]; \
        }                                                                      \
    }

    {
        f32x4 acc[8];
#pragma unroll
        for (int t = 0; t < 8; ++t) acc[t] = (f32x4){0.f, 0.f, 0.f, 0.f};
        COMPUTE(acc);
        int g1 = g0 + 2048;
        bool has2 = g1 < NG16;
        if (has2) LDALL(g1);   // issue under the epilogue's shfl/VALU
        EPILOGUE(acc);
        if (has2) {
            f32x4 acc2[8];
#pragma unroll
            for (int t = 0; t < 8; ++t) acc2[t] = (f32x4){0.f, 0.f, 0.f, 0.f};
            COMPUTE(acc2);
            EPILOGUE(acc2);
        }
    }
#undef LDALL
#undef COMPUTE
#undef EPILOGUE

    // pool: lane holds cols {tile*16 + c16}; reduce across kg via shfl
#pragma unroll
    for (int tile = 0; tile < 8; ++tile) {
        float t = pacc[tile] + __shfl_xor(pacc[tile], 16);
        t += __shfl_xor(t, 32);
        if (kg == 0) atomicAdd(&pooled_sh[tile * 16 + c16], t);
    }
    __syncthreads();
    if (threadIdx.x < HID) atomicAdd(&pooled[threadIdx.x], pooled_sh[threadIdx.x]);

    // ---- folded final reduction (last block) ----
    __threadfence();
    __syncthreads();
    if (threadIdx.x == 0)
        lastFlag = (atomicAdd(done, 1) == (int)gridDim.x - 1);
    __syncthreads();
    if (lastFlag && threadIdx.x < 64) {
        int l = threadIdx.x;
        // atomic fetch-add(0) reads take the same coherent path as the writes
        float s = atomicAdd(&pooled[l], 0.0f) * reg_w[l] +
                  atomicAdd(&pooled[64 + l], 0.0f) * reg_w[64 + l];
#pragma unroll
        for (int o = 32; o; o >>= 1) s += __shfl_down(s, o);
        if (l == 0) out[0] = s * (1.0f / N_NODES) + reg_b[0];
    }
}

// ---------------------------------------------------------------------------
extern "C" void kernel_launch(void* const* d_in, const int* in_sizes, int n_in,
                              void* d_out, int out_size, void* d_ws, size_t ws_size,
                              hipStream_t stream) {
    const int* z = (const int*)d_in[0];
    const int* nt = (const int*)d_in[1];
    const int* ei = (const int*)d_in[2];
    const int* et = (const int*)d_in[3];
    const float* z_embed = (const float*)d_in[4];
    const float* enc_w1 = (const float*)d_in[5];
    const float* enc_b1 = (const float*)d_in[6];
    const float* enc_w2 = (const float*)d_in[7];
    const float* enc_b2 = (const float*)d_in[8];
    const float* lin_w = (const float*)d_in[9];
    const float* lin_b = (const float*)d_in[10];
    const float* rel_w = (const float*)d_in[11];
    const float* ln_g = (const float*)d_in[12];
    const float* ln_b = (const float*)d_in[13];
    const float* reg_w = (const float*)d_in[14];
    const float* reg_b = (const float*)d_in[15];
    float* out = (float*)d_out;

    const size_t NHf8 = (size_t)NROWS * HID;  // bytes per fp8 feature plane
    char* p = (char*)d_ws;
    uint2* xf8 = (uint2*)p;                     p += NHf8;   // 6.4 MB
    uint2* s0 = (uint2*)p;                      p += NHf8;   // fp8 means
    uint2* s1 = (uint2*)p;                      p += NHf8;
    uint2* s2 = (uint2*)p;                      p += NHf8;
    unsigned short* wbuf = (unsigned short*)p;  p += (size_t)4 * HID * WT_STRIDE * 2;
    unsigned int* ytab = (unsigned int*)p;      p += (size_t)N_REL * NCOMBO * HID;  // fp8
    float* lintab = (float*)p;                  p += NCOMBO * HID * 4;
    unsigned short* combo = (unsigned short*)p; p += N_NODES * 2;
    float* pooled = (float*)p;                  p += HID * 4;
    int* cnt3 = (int*)p;                        p += N_NODES * 4;
    int* bcnt = (int*)p;                        p += NBKT * 4;
    int* done = (int*)p;                        p += 4;        // adjacent to bcnt
    int* bucket = (int*)p;                      p += (size_t)NBKT * CAP1 * 4;
    int* payload = (int*)p;                     p += (size_t)N_NODES * CAP * 4;

    const int* src = ei;
    const int* dst = ei + N_EDGES;

    hipMemsetAsync(bcnt, 0, (NBKT + 1) * sizeof(int), stream);  // bcnt + done

    // front-end: edge binning || encoder tables || weight prep (one dispatch)
    build_tables_kernel<<<NBKT + NCOMBO + 256, 256, 0, stream>>>(
        src, dst, et, z, nt, z_embed, enc_w1, enc_b1, enc_w2, enc_b2,
        rel_w, lin_w, lin_b, combo, bcnt, bucket, ytab, lintab, wbuf, pooled);

    build2_kernel<<<NBKT, 256, 0, stream>>>(bcnt, bucket, combo, cnt3, payload);

    // layer 1: fused fp8 table-gather + lin + LN -> xf8 (fp8)
    gather_ln1_kernel<<<3125, 256, 0, stream>>>(cnt3, payload, (const uint2*)ytab, lintab,
                                                combo, ln_g, ln_b, xf8);
    // layer 2: fp8 gather -> fp8 means; 16x16 MFMA fused layer
    gather3_kernel<<<3125, 256, 0, stream>>>(cnt3, payload, xf8, s0, s1, s2);
    fused_layer_kernel<<<256, 512, 0, stream>>>(
        s0, s1, s2, xf8, (const uint4*)wbuf, lin_b + HID, ln_g + HID, ln_b + HID,
        pooled, reg_w, reg_b, out, done);
}